// Round 1
// baseline (180.325 us; speedup 1.0000x reference)
//
#include <hip/hip_runtime.h>
#include <math.h>

#define NB   256   // batch N
#define LL   64
#define FF   32
#define KIN  2048  // L*F
#define OKD  1024  // OUT_FEATURES*KERNEL_DIMS
#define OUTF 64
#define KD   16

// ---------------- K1: vraw[j] = sum_i W[i,j]*u[i]  (W^T u) ----------------
// grid (8 col-blocks, 8 row-blocks) x 256 threads
__global__ void k_vraw(const float* __restrict__ W, const float* __restrict__ u,
                       float* __restrict__ vraw) {
    int j  = blockIdx.x * 256 + threadIdx.x;   // 0..2047
    int i0 = blockIdx.y * 128;
    float s = 0.f;
#pragma unroll 4
    for (int i = 0; i < 128; ++i) {
        s += W[(size_t)(i0 + i) * KIN + j] * u[i0 + i];
    }
    atomicAdd(&vraw[j], s);
}

// ---------------- K2: v = vraw / (||vraw|| + eps) ----------------
// 1 block x 256 threads
__global__ void k_vnorm(const float* __restrict__ vraw, float* __restrict__ v) {
    __shared__ float wsum[4];
    int tid = threadIdx.x;
    float a[8];
    float ss = 0.f;
#pragma unroll
    for (int q = 0; q < 8; ++q) { a[q] = vraw[tid + q * 256]; ss += a[q] * a[q]; }
#pragma unroll
    for (int off = 32; off; off >>= 1) ss += __shfl_xor(ss, off);
    if ((tid & 63) == 0) wsum[tid >> 6] = ss;
    __syncthreads();
    float tot = wsum[0] + wsum[1] + wsum[2] + wsum[3];
    float inv = 1.f / (sqrtf(tot) + 1e-12f);
#pragma unroll
    for (int q = 0; q < 8; ++q) v[tid + q * 256] = a[q] * inv;
}

// ---------------- K3: sumsq_t = || W v ||^2  (t never needed itself) ----------------
// grid 256 x 256 threads: wave per row, 4 rows/block
__global__ void k_t(const float* __restrict__ W, const float* __restrict__ v,
                    float* __restrict__ sumsq_t) {
    int w = threadIdx.x >> 6, lane = threadIdx.x & 63;
    int i = blockIdx.x * 4 + w;                 // 0..1023
    const float4* W4 = (const float4*)(W + (size_t)i * KIN);
    const float4* v4 = (const float4*)v;
    float s = 0.f;
#pragma unroll
    for (int q = 0; q < 8; ++q) {
        float4 a = W4[q * 64 + lane];
        float4 bb = v4[q * 64 + lane];
        s += a.x * bb.x + a.y * bb.y + a.z * bb.z + a.w * bb.w;
    }
#pragma unroll
    for (int off = 32; off; off >>= 1) s += __shfl_xor(s, off);
    if (lane == 0) atomicAdd(sumsq_t, s * s);
}

// ---------------- K4: M[n,oc] = dot(x[n,:], W[oc,:]) / sigma + b[oc] ----------------
// 32x32 tile, 256 threads, 2x2 microtile. grid (1024/32, 256/32)
__global__ __launch_bounds__(256) void k_gemm(const float* __restrict__ X,
                                              const float* __restrict__ W,
                                              const float* __restrict__ bias,
                                              const float* __restrict__ sumsq_t,
                                              float* __restrict__ M) {
    __shared__ float As[32][33];
    __shared__ float Bs[32][33];
    int tid = threadIdx.x;
    int br = blockIdx.y * 32;          // n rows
    int bc = blockIdx.x * 32;          // oc cols
    int lr = tid >> 3, lq = tid & 7;   // staging: row 0..31, float4 idx 0..7
    int tx = tid & 15, ty = tid >> 4;  // compute: 16x16 threads, 2x2 each
    float acc00 = 0.f, acc01 = 0.f, acc10 = 0.f, acc11 = 0.f;

    for (int kt = 0; kt < KIN / 32; ++kt) {
        float4 av = *(const float4*)(X + (size_t)(br + lr) * KIN + kt * 32 + lq * 4);
        float4 bv = *(const float4*)(W + (size_t)(bc + lr) * KIN + kt * 32 + lq * 4);
        __syncthreads();
        As[lr][lq * 4 + 0] = av.x; As[lr][lq * 4 + 1] = av.y;
        As[lr][lq * 4 + 2] = av.z; As[lr][lq * 4 + 3] = av.w;
        Bs[lr][lq * 4 + 0] = bv.x; Bs[lr][lq * 4 + 1] = bv.y;
        Bs[lr][lq * 4 + 2] = bv.z; Bs[lr][lq * 4 + 3] = bv.w;
        __syncthreads();
#pragma unroll
        for (int kk = 0; kk < 32; ++kk) {
            float a0 = As[ty * 2 + 0][kk], a1 = As[ty * 2 + 1][kk];
            float b0 = Bs[tx * 2 + 0][kk], b1 = Bs[tx * 2 + 1][kk];
            acc00 += a0 * b0; acc01 += a0 * b1;
            acc10 += a1 * b0; acc11 += a1 * b1;
        }
    }
    float ssq = *sumsq_t;
    float sigma = ssq / (sqrtf(ssq) + 1e-12f);  // = u_new @ (W v)
    float inv = 1.f / sigma;
    int r0 = br + ty * 2, c0 = bc + tx * 2;
    float bb0 = bias[c0], bb1 = bias[c0 + 1];
    M[(size_t)r0 * OKD + c0]           = acc00 * inv + bb0;
    M[(size_t)r0 * OKD + c0 + 1]       = acc01 * inv + bb1;
    M[(size_t)(r0 + 1) * OKD + c0]     = acc10 * inv + bb0;
    M[(size_t)(r0 + 1) * OKD + c0 + 1] = acc11 * inv + bb1;
}

// ---------------- K5: ob[n,o] = sum_j exp(-sum_k |M[n,o,k]-M[j,o,k]|) - 1 ----------------
// grid (64 o, 4 n-chunks) x 256 threads. 4 threads cooperate per n over j.
__global__ __launch_bounds__(256) void k_pair(const float* __restrict__ M,
                                              float* __restrict__ ob) {
    __shared__ float sm[NB * KD];   // 16 KB: M[:, o, :]
    int o = blockIdx.x;
    int tid = threadIdx.x;
    const float4* M4 = (const float4*)M;
    float4* sm4 = (float4*)sm;
#pragma unroll
    for (int tq = 0; tq < 4; ++tq) {
        int idx = tid + tq * 256;       // 0..1023 float4s
        int j = idx >> 2, k4 = idx & 3;
        sm4[idx] = M4[j * 256 + o * 4 + k4];
    }
    __syncthreads();
    int n  = blockIdx.y * 64 + (tid >> 2);
    int jc = tid & 3;
    float r[KD];
#pragma unroll
    for (int k = 0; k < KD; ++k) r[k] = sm[n * KD + k];
    float acc = 0.f;
    for (int jj = 0; jj < 64; ++jj) {
        int j = jj * 4 + jc;            // interleave: lane-groups hit different banks
        float d = 0.f;
#pragma unroll
        for (int k = 0; k < KD; ++k) d += fabsf(r[k] - sm[j * KD + k]);
        acc += __expf(-d);
    }
    acc += __shfl_xor(acc, 1);
    acc += __shfl_xor(acc, 2);
    if (jc == 0) ob[n * OUTF + o] = acc - 1.0f;   // remove self term exp(0)=1
}

// ---------------- K6: out[n,l,:] = concat(x[n,l,:], ob[n,:]) ----------------
// 96 floats per (n,l) = 24 float4. total 256*64*24 = 393216 float4.
__global__ void k_out(const float* __restrict__ X, const float* __restrict__ ob,
                      float4* __restrict__ out4) {
    int q = blockIdx.x * 256 + threadIdx.x;
    int r = q / 24;              // (n,l) row
    int c = q - r * 24;          // float4 within row
    if (c < 8) {
        out4[q] = ((const float4*)X)[r * 8 + c];
    } else {
        int n = r >> 6;
        out4[q] = ((const float4*)ob)[n * 16 + (c - 8)];
    }
}

extern "C" void kernel_launch(void* const* d_in, const int* in_sizes, int n_in,
                              void* d_out, int out_size, void* d_ws, size_t ws_size,
                              hipStream_t stream) {
    const float* x = (const float*)d_in[0];   // 256*64*32
    const float* W = (const float*)d_in[1];   // 1024*2048
    const float* b = (const float*)d_in[2];   // 1024
    const float* u = (const float*)d_in[3];   // 1024

    float* ws   = (float*)d_ws;
    float* vraw = ws;                  // 2048
    float* v    = ws + 2048;           // 2048
    float* ssq  = ws + 5120;           // 1
    float* M    = ws + 8192;           // 256*1024
    float* ob   = ws + 8192 + NB * OKD; // 256*64

    // zero the atomic-accumulated region (ws is poisoned 0xAA each call)
    hipMemsetAsync(d_ws, 0, 5121 * sizeof(float), stream);

    k_vraw <<<dim3(8, 8),  256, 0, stream>>>(W, u, vraw);
    k_vnorm<<<1,           256, 0, stream>>>(vraw, v);
    k_t    <<<256,         256, 0, stream>>>(W, v, ssq);
    k_gemm <<<dim3(32, 8), 256, 0, stream>>>(x, W, b, ssq, M);
    k_pair <<<dim3(64, 4), 256, 0, stream>>>(M, ob);
    k_out  <<<1536,        256, 0, stream>>>(x, ob, (float4*)d_out);
}

// Round 5
// 178.191 us; speedup vs baseline: 1.0120x; 1.0120x over previous
//
#include <hip/hip_runtime.h>
#include <hip/hip_bf16.h>
#include <math.h>

#define KIN  2048
#define OKD  1024
#define NB   256
#define OUTF 64
#define KD   16

typedef float f32x4  __attribute__((ext_vector_type(4)));
typedef short bf16x4 __attribute__((ext_vector_type(4)));
typedef short bf16x8 __attribute__((ext_vector_type(8)));
typedef unsigned short u16x8 __attribute__((ext_vector_type(8)));

static __device__ __forceinline__ unsigned short f2bf(float f) {
    union { __hip_bfloat16 b; unsigned short u; } cv;
    cv.b = __float2bfloat16(f);
    return cv.u;
}
static __device__ __forceinline__ float bf2f(unsigned short u) {
    union { unsigned int i; float f; } cv; cv.i = ((unsigned int)u) << 16; return cv.f;
}
static __device__ __forceinline__ u16x8 pack8(float4 a, float4 b) {
    u16x8 r;
    r[0]=f2bf(a.x); r[1]=f2bf(a.y); r[2]=f2bf(a.z); r[3]=f2bf(a.w);
    r[4]=f2bf(b.x); r[5]=f2bf(b.y); r[6]=f2bf(b.z); r[7]=f2bf(b.w);
    return r;
}

// ---- K1: fused W fp32->bf16 cast + vraw = W^T u (fp32 inputs for accuracy) ----
// grid 256 blocks x 256 thr; block covers 4 rows x all 2048 cols (8 cols/thread)
__global__ __launch_bounds__(256) void k_vraw_cast(const float* __restrict__ W,
        const float* __restrict__ u, float* __restrict__ vraw,
        unsigned short* __restrict__ Wb) {
    int tid = threadIdx.x;
    int row0 = blockIdx.x * 4;
    int c = tid * 8;
    float s[8];
#pragma unroll
    for (int i = 0; i < 8; ++i) s[i] = 0.f;
#pragma unroll
    for (int r = 0; r < 4; ++r) {
        int row = row0 + r;
        const float4* src = (const float4*)(W + (size_t)row * KIN + c);
        float4 f0 = src[0], f1 = src[1];
        *(u16x8*)(Wb + (size_t)row * KIN + c) = pack8(f0, f1);
        float uu = u[row];
        s[0] += f0.x * uu; s[1] += f0.y * uu; s[2] += f0.z * uu; s[3] += f0.w * uu;
        s[4] += f1.x * uu; s[5] += f1.y * uu; s[6] += f1.z * uu; s[7] += f1.w * uu;
    }
#pragma unroll
    for (int i = 0; i < 8; ++i) atomicAdd(&vraw[c + i], s[i]);
}

// ---- K2: x fp32 -> bf16 ----
__global__ void k_xcast(const float* __restrict__ x, unsigned short* __restrict__ xb) {
    int g = blockIdx.x * 256 + threadIdx.x;
    const float4* s = (const float4*)x + (size_t)g * 2;
    float4 f0 = s[0], f1 = s[1];
    *((u16x8*)xb + g) = pack8(f0, f1);
}

// ---- K3: v = vraw / (||vraw|| + eps) ----
__global__ void k_vnorm(const float* __restrict__ vraw, float* __restrict__ v) {
    __shared__ float wsum[4];
    int tid = threadIdx.x;
    float a[8];
    float ss = 0.f;
#pragma unroll
    for (int q = 0; q < 8; ++q) { a[q] = vraw[tid + q * 256]; ss += a[q] * a[q]; }
#pragma unroll
    for (int off = 32; off; off >>= 1) ss += __shfl_xor(ss, off);
    if ((tid & 63) == 0) wsum[tid >> 6] = ss;
    __syncthreads();
    float tot = wsum[0] + wsum[1] + wsum[2] + wsum[3];
    float inv = 1.f / (sqrtf(tot) + 1e-12f);
#pragma unroll
    for (int q = 0; q < 8; ++q) v[tid + q * 256] = a[q] * inv;
}

// ---- K4: ssq = ||W v||^2  (bf16 W) ----
// grid 512 blocks x 256 thr: 2 rows/block, 2 waves per row (1024 k each)
__global__ __launch_bounds__(256) void k_t(const unsigned short* __restrict__ Wb,
        const float* __restrict__ v, float* __restrict__ ssq) {
    __shared__ float part[4];
    int tid = threadIdx.x, lane = tid & 63, w = tid >> 6;
    int row = blockIdx.x * 2 + (w >> 1);
    int h = w & 1;
    const u16x8* W8 = (const u16x8*)(Wb + (size_t)row * KIN + h * 1024);
    const float4* v4 = (const float4*)(v + h * 1024);
    float s = 0.f;
#pragma unroll
    for (int q = 0; q < 2; ++q) {
        u16x8 a = W8[q * 64 + lane];
        float4 b0 = v4[(q * 64 + lane) * 2];
        float4 b1 = v4[(q * 64 + lane) * 2 + 1];
        s += bf2f(a[0]) * b0.x + bf2f(a[1]) * b0.y + bf2f(a[2]) * b0.z + bf2f(a[3]) * b0.w;
        s += bf2f(a[4]) * b1.x + bf2f(a[5]) * b1.y + bf2f(a[6]) * b1.z + bf2f(a[7]) * b1.w;
    }
#pragma unroll
    for (int off = 32; off; off >>= 1) s += __shfl_xor(s, off);
    if (lane == 0) part[w] = s;
    __syncthreads();
    if (tid == 0) {
        float r0 = part[0] + part[1], r1 = part[2] + part[3];
        atomicAdd(ssq, r0 * r0 + r1 * r1);
    }
}

// ---- K5: M[n][c] = bias[c] (init for split-K atomics) ----
__global__ void k_minit(const float4* __restrict__ b4, float4* __restrict__ M4) {
    int g = blockIdx.x * 256 + threadIdx.x;
    M4[g] = b4[g & 255];
}

// ---- K6: MFMA bf16 GEMM, split-K=8, 64x64 tile, atomicAdd epilogue ----
// frag layout (16x16x32 bf16): A/B row|col = lane&15, k = 4*(lane>>4)+{0..3} and +16
// C/D: col = lane&15, row = 4*(lane>>4)+reg
static __device__ __forceinline__ bf16x8 load_frag(const unsigned short* lds, int row, int k0) {
    int b0 = (row << 7) + (k0 << 1);
    b0 ^= (row & 7) << 4;                 // XOR swizzle (bank-conflict fix)
    bf16x4 lo = *(const bf16x4*)((const char*)lds + b0);
    bf16x4 hi = *(const bf16x4*)((const char*)lds + (b0 ^ 32)); // +16 k, same swizzle bits
    bf16x8 r;
    r[0]=lo[0]; r[1]=lo[1]; r[2]=lo[2]; r[3]=lo[3];
    r[4]=hi[0]; r[5]=hi[1]; r[6]=hi[2]; r[7]=hi[3];
    return r;
}

__global__ __launch_bounds__(256) void k_gemm(const unsigned short* __restrict__ xb,
        const unsigned short* __restrict__ Wb, const float* __restrict__ ssqp,
        float* __restrict__ M) {
    __shared__ unsigned short sAB[8192];   // A tile 64x64 bf16 | B tile 64x64 bf16
    int tid = threadIdx.x;
    int lane = tid & 63, w = tid >> 6;
    int c0 = blockIdx.x * 64, n0 = blockIdx.y * 64, kb0 = blockIdx.z * 256;

    // staging: 16 chunks of 1KB; chunk ch = q*4+w; LDS linear, global pre-swizzled
    const char* gq[4];
    unsigned short* lq[4];
#pragma unroll
    for (int q = 0; q < 4; ++q) {
        int ch = q * 4 + w;
        int p = ch * 1024 + lane * 16;     // byte pos in 16KB combined region
        int rp = p & 8191;                 // byte within A or B region
        int row = rp >> 7;                 // 128B per row (64 bf16)
        int off = (rp & 127) ^ ((row & 7) << 4);   // inverse-swizzled source
        const unsigned short* base = (ch < 8) ? xb : Wb;
        int grow = (ch < 8) ? (n0 + row) : (c0 + row);
        gq[q] = (const char*)(base + (size_t)grow * KIN) + off;
        lq[q] = sAB + ch * 512;            // wave-uniform (ch depends only on w,q)
    }

    int g = lane >> 4, cl = lane & 15;
    int wy = w >> 1, wx = w & 1;
    f32x4 acc[2][2];
#pragma unroll
    for (int i = 0; i < 2; ++i)
#pragma unroll
        for (int j = 0; j < 2; ++j)
#pragma unroll
            for (int r = 0; r < 4; ++r) acc[i][j][r] = 0.f;

    const unsigned short* sA = sAB;
    const unsigned short* sB = sAB + 4096;

    for (int st = 0; st < 4; ++st) {
        int kbyte = (kb0 + st * 64) * 2;
        __syncthreads();
#pragma unroll
        for (int q = 0; q < 4; ++q)
            __builtin_amdgcn_global_load_lds(
                (const __attribute__((address_space(1))) unsigned int*)(gq[q] + kbyte),
                (__attribute__((address_space(3))) unsigned int*)lq[q], 16, 0, 0);
        __syncthreads();
#pragma unroll
        for (int s = 0; s < 2; ++s) {
            int k0 = s * 32 + 4 * g;
            bf16x8 af[2], bfr[2];
#pragma unroll
            for (int mi = 0; mi < 2; ++mi)
                af[mi] = load_frag(sA, wy * 32 + mi * 16 + cl, k0);
#pragma unroll
            for (int ni = 0; ni < 2; ++ni)
                bfr[ni] = load_frag(sB, wx * 32 + ni * 16 + cl, k0);
#pragma unroll
            for (int mi = 0; mi < 2; ++mi)
#pragma unroll
                for (int ni = 0; ni < 2; ++ni)
                    acc[mi][ni] = __builtin_amdgcn_mfma_f32_16x16x32_bf16(
                        af[mi], bfr[ni], acc[mi][ni], 0, 0, 0);
        }
    }

    float sq = *ssqp;
    float scale = (sqrtf(sq) + 1e-12f) / sq;   // 1/sigma
#pragma unroll
    for (int mi = 0; mi < 2; ++mi)
#pragma unroll
        for (int ni = 0; ni < 2; ++ni) {
            int row = n0 + wy * 32 + mi * 16 + 4 * g;
            int col = c0 + wx * 32 + ni * 16 + cl;
            float* mp = M + (size_t)row * OKD + col;
#pragma unroll
            for (int r = 0; r < 4; ++r)
                atomicAdd(mp + r * OKD, acc[mi][ni][r] * scale);
        }
}

// ---- K7: ob[n,o] = sum_j exp(-L1(m[n,o,:], m[j,o,:])) - 1 ----
// grid (64 o, 8 n-chunks of 32) x 256 thr; 8 lanes cooperate per n over j
__global__ __launch_bounds__(256) void k_pair(const float* __restrict__ M,
                                              float* __restrict__ ob) {
    __shared__ float sm[NB * KD];   // 16 KB, XOR-swizzled by row
    int o = blockIdx.x, tid = threadIdx.x;
    const float4* M4 = (const float4*)M;
    float4* sm4 = (float4*)sm;
#pragma unroll
    for (int tq = 0; tq < 4; ++tq) {
        int idx = tid + tq * 256;          // 1024 float4
        int j = idx >> 2, k4 = idx & 3;
        sm4[j * 4 + (k4 ^ (j & 3))] = M4[(size_t)j * 256 + o * 4 + k4];
    }
    __syncthreads();
    int n = blockIdx.y * 32 + (tid >> 3);
    int jc = tid & 7;
    int nx = (n & 3) << 2;
    float r[KD];
#pragma unroll
    for (int k = 0; k < KD; ++k) r[k] = sm[n * 16 + (k ^ nx)];
    float acc = 0.f;
    for (int jj = 0; jj < 32; ++jj) {
        int j = jj * 8 + jc;
        int base = j * 16, jx = (j & 3) << 2;
        float d = 0.f;
#pragma unroll
        for (int k = 0; k < KD; ++k) d += fabsf(r[k] - sm[base + (k ^ jx)]);
        acc += __expf(-d);
    }
    acc += __shfl_xor(acc, 1);
    acc += __shfl_xor(acc, 2);
    acc += __shfl_xor(acc, 4);
    if (jc == 0) ob[n * OUTF + o] = acc - 1.0f;
}

// ---- K8: out[n,l,:] = concat(x[n,l,:], ob[n,:]) ----
__global__ void k_out(const float* __restrict__ X, const float* __restrict__ ob,
                      float4* __restrict__ out4) {
    int q = blockIdx.x * 256 + threadIdx.x;
    int r = q / 24;
    int c = q - r * 24;
    if (c < 8) {
        out4[q] = ((const float4*)X)[(size_t)r * 8 + c];
    } else {
        int n = r >> 6;
        out4[q] = ((const float4*)ob)[n * 16 + (c - 8)];
    }
}

extern "C" void kernel_launch(void* const* d_in, const int* in_sizes, int n_in,
                              void* d_out, int out_size, void* d_ws, size_t ws_size,
                              hipStream_t stream) {
    const float* x = (const float*)d_in[0];   // 256*64*32
    const float* W = (const float*)d_in[1];   // 1024*2048
    const float* b = (const float*)d_in[2];   // 1024
    const float* u = (const float*)d_in[3];   // 1024

    float* ws = (float*)d_ws;
    float* vraw = ws;                                  // 2048
    float* ssq  = ws + 2048;                           // 1
    float* v    = ws + 2560;                           // 2048
    float* M    = ws + 8192;                           // 262144
    unsigned short* Wb = (unsigned short*)(ws + 270336);          // 2M bf16 (4MB)
    unsigned short* xb = (unsigned short*)(ws + 270336 + 1048576); // 512K bf16 (1MB)
    float* ob   = ws + 1581056;                        // 16384

    hipMemsetAsync(ws, 0, 2049 * sizeof(float), stream);  // vraw + ssq

    k_vraw_cast<<<256, 256, 0, stream>>>(W, u, vraw, Wb);
    k_xcast    <<<256, 256, 0, stream>>>(x, xb);
    k_vnorm    <<<1,   256, 0, stream>>>(vraw, v);
    k_t        <<<512, 256, 0, stream>>>(Wb, v, ssq);
    k_minit    <<<256, 256, 0, stream>>>((const float4*)b, (float4*)M);
    k_gemm     <<<dim3(16, 4, 8), 256, 0, stream>>>(xb, Wb, ssq, M);
    k_pair     <<<dim3(64, 8),    256, 0, stream>>>(M, ob);
    k_out      <<<1536, 256, 0, stream>>>(x, ob, (float4*)d_out);
}

// Round 8
// 104.845 us; speedup vs baseline: 1.7199x; 1.6996x over previous
//
#include <hip/hip_runtime.h>
#include <hip/hip_bf16.h>
#include <math.h>

#define KIN  2048
#define OKD  1024
#define NB   256
#define OUTF 64
#define KD   16

typedef float f32x4  __attribute__((ext_vector_type(4)));
typedef short bf16x4 __attribute__((ext_vector_type(4)));
typedef short bf16x8 __attribute__((ext_vector_type(8)));
typedef unsigned short u16x8 __attribute__((ext_vector_type(8)));

static __device__ __forceinline__ unsigned short f2bf(float f) {
    union { __hip_bfloat16 b; unsigned short u; } cv;
    cv.b = __float2bfloat16(f);
    return cv.u;
}
static __device__ __forceinline__ u16x8 pack8(float4 a, float4 b) {
    u16x8 r;
    r[0]=f2bf(a.x); r[1]=f2bf(a.y); r[2]=f2bf(a.z); r[3]=f2bf(a.w);
    r[4]=f2bf(b.x); r[5]=f2bf(b.y); r[6]=f2bf(b.z); r[7]=f2bf(b.w);
    return r;
}
static __device__ __forceinline__ float bf2f(unsigned short u) {
    union { unsigned int i; float f; } cv; cv.i = ((unsigned int)u) << 16; return cv.f;
}

// ---- K1: fused W fp32->bf16 cast + per-block partial of W^T u (NO atomics) ----
// grid 128 x 256 thr; block covers 8 rows x 2048 cols; writes partial[bid][2048]
__global__ __launch_bounds__(256) void k_vraw_cast(const float* __restrict__ W,
        const float* __restrict__ u, float* __restrict__ partial,
        unsigned short* __restrict__ Wb) {
    int tid = threadIdx.x;
    int row0 = blockIdx.x * 8;
    int c = tid * 8;
    float s[8];
#pragma unroll
    for (int i = 0; i < 8; ++i) s[i] = 0.f;
#pragma unroll
    for (int r = 0; r < 8; ++r) {
        int row = row0 + r;
        const float4* src = (const float4*)(W + (size_t)row * KIN + c);
        float4 f0 = src[0], f1 = src[1];
        *(u16x8*)(Wb + (size_t)row * KIN + c) = pack8(f0, f1);
        float uu = u[row];
        s[0] += f0.x * uu; s[1] += f0.y * uu; s[2] += f0.z * uu; s[3] += f0.w * uu;
        s[4] += f1.x * uu; s[5] += f1.y * uu; s[6] += f1.z * uu; s[7] += f1.w * uu;
    }
    float4* dst = (float4*)(partial + (size_t)blockIdx.x * KIN + c);
    dst[0] = make_float4(s[0], s[1], s[2], s[3]);
    dst[1] = make_float4(s[4], s[5], s[6], s[7]);
}

// ---- K2 (merged): blocks 0..15 reduce partial 128->2; blocks 16..271 cast x->bf16 ----
__global__ __launch_bounds__(256) void k_vredx(const float* __restrict__ partial,
        float* __restrict__ partial2, const float* __restrict__ x,
        unsigned short* __restrict__ xb) {
    int bid = blockIdx.x, tid = threadIdx.x;
    if (bid >= 16) {
        int g = (bid - 16) * 256 + tid;
        const float4* s = (const float4*)x + (size_t)g * 2;
        float4 f0 = s[0], f1 = s[1];
        *((u16x8*)xb + g) = pack8(f0, f1);
        return;
    }
    int cg = bid & 7, bg = bid >> 3;          // cols cg*256..+256, b-range bg*64..+64
    int col = cg * 256 + tid;
    float a = 0.f;
#pragma unroll 8
    for (int i = 0; i < 64; ++i)
        a += partial[(size_t)(bg * 64 + i) * KIN + col];
    partial2[bg * KIN + col] = a;
}

// ---- K3: v = vraw / (||vraw|| + eps), vraw = partial2[0]+partial2[1] ----
__global__ void k_vnorm(const float* __restrict__ partial2, float* __restrict__ v) {
    __shared__ float wsum[4];
    int tid = threadIdx.x;
    float a[8];
    float ss = 0.f;
#pragma unroll
    for (int q = 0; q < 8; ++q) {
        int col = tid + q * 256;
        a[q] = partial2[col] + partial2[KIN + col];
        ss += a[q] * a[q];
    }
#pragma unroll
    for (int off = 32; off; off >>= 1) ss += __shfl_xor(ss, off);
    if ((tid & 63) == 0) wsum[tid >> 6] = ss;
    __syncthreads();
    float tot = wsum[0] + wsum[1] + wsum[2] + wsum[3];
    float inv = 1.f / (sqrtf(tot) + 1e-12f);
#pragma unroll
    for (int q = 0; q < 8; ++q) v[tid + q * 256] = a[q] * inv;
}

// ---- K4: tpart[bid] = sum of squared row-dots for 2 rows (NO atomics) ----
// grid 512 x 256 thr: 2 rows/block, 2 waves per row
__global__ __launch_bounds__(256) void k_t(const unsigned short* __restrict__ Wb,
        const float* __restrict__ v, float* __restrict__ tpart) {
    __shared__ float part[4];
    int tid = threadIdx.x, lane = tid & 63, w = tid >> 6;
    int row = blockIdx.x * 2 + (w >> 1);
    int h = w & 1;
    const u16x8* W8 = (const u16x8*)(Wb + (size_t)row * KIN + h * 1024);
    const float4* v4 = (const float4*)(v + h * 1024);
    float s = 0.f;
#pragma unroll
    for (int q = 0; q < 2; ++q) {
        u16x8 a = W8[q * 64 + lane];
        float4 b0 = v4[(q * 64 + lane) * 2];
        float4 b1 = v4[(q * 64 + lane) * 2 + 1];
        s += bf2f(a[0]) * b0.x + bf2f(a[1]) * b0.y + bf2f(a[2]) * b0.z + bf2f(a[3]) * b0.w;
        s += bf2f(a[4]) * b1.x + bf2f(a[5]) * b1.y + bf2f(a[6]) * b1.z + bf2f(a[7]) * b1.w;
    }
#pragma unroll
    for (int off = 32; off; off >>= 1) s += __shfl_xor(s, off);
    if (lane == 0) part[w] = s;
    __syncthreads();
    if (tid == 0) {
        float r0 = part[0] + part[1], r1 = part[2] + part[3];
        tpart[blockIdx.x] = r0 * r0 + r1 * r1;
    }
}

// ---- K5: MFMA bf16 GEMM, 32x32 tile, full K, plain stores (NO atomics) ----
// frag layout (16x16x32 bf16): A/B row|col = lane&15, k = 4*(lane>>4)+{0..3} and +16
// C/D: col = lane&15, row = 4*(lane>>4)+reg
static __device__ __forceinline__ bf16x8 load_frag(const unsigned short* lds, int row, int k0) {
    int b0 = (row << 7) + (k0 << 1);
    b0 ^= (row & 7) << 4;                 // XOR swizzle (bank-conflict fix)
    bf16x4 lo = *(const bf16x4*)((const char*)lds + b0);
    bf16x4 hi = *(const bf16x4*)((const char*)lds + (b0 ^ 32)); // +16 k, same swizzle
    bf16x8 r;
    r[0]=lo[0]; r[1]=lo[1]; r[2]=lo[2]; r[3]=lo[3];
    r[4]=hi[0]; r[5]=hi[1]; r[6]=hi[2]; r[7]=hi[3];
    return r;
}

__global__ __launch_bounds__(256) void k_gemm(const unsigned short* __restrict__ xb,
        const unsigned short* __restrict__ Wb, const float* __restrict__ tpart,
        const float* __restrict__ bias, float* __restrict__ M) {
    __shared__ unsigned short sAB[4096];   // A 32x64 | B 32x64 bf16 (8 KB)
    __shared__ float red[4];
    __shared__ float s_inv;
    int tid = threadIdx.x;
    int lane = tid & 63, w = tid >> 6;
    int c0 = blockIdx.x * 32, n0 = blockIdx.y * 32;

    // ---- sigma from tpart (512 plain partials; cheap block-redundant reduce) ----
    float sv = tpart[tid] + tpart[tid + 256];
#pragma unroll
    for (int off = 32; off; off >>= 1) sv += __shfl_xor(sv, off);
    if (lane == 0) red[w] = sv;
    __syncthreads();
    if (tid == 0) {
        float ssq = red[0] + red[1] + red[2] + red[3];
        s_inv = (sqrtf(ssq) + 1e-12f) / ssq;   // 1/sigma
    }

    // staging: 8 chunks of 1KB; chunk ch = q*4+w; LDS linear, global pre-swizzled
    const char* gq[2];
    unsigned short* lq[2];
#pragma unroll
    for (int q = 0; q < 2; ++q) {
        int ch = q * 4 + w;
        int p = ch * 1024 + lane * 16;     // byte pos in 8KB combined region
        int rp = p & 4095;                 // byte within A or B region
        int row = rp >> 7;                 // 128B per row (64 bf16), row 0..31
        int off = (rp & 127) ^ ((row & 7) << 4);   // inverse-swizzled source
        const unsigned short* base = (p < 4096) ? xb : Wb;
        int grow = (p < 4096) ? (n0 + row) : (c0 + row);
        gq[q] = (const char*)(base + (size_t)grow * KIN) + off;
        lq[q] = sAB + ch * 512;            // wave-uniform (ch depends only on w,q)
    }

    int g = lane >> 4, cl = lane & 15;
    int wy = w >> 1, wx = w & 1;
    f32x4 acc;
#pragma unroll
    for (int r = 0; r < 4; ++r) acc[r] = 0.f;

    const unsigned short* sA = sAB;
    const unsigned short* sB = sAB + 2048;

    for (int t = 0; t < 32; ++t) {
        int kbyte = t * 128;               // 64 bf16 per chunk
        __syncthreads();
#pragma unroll
        for (int q = 0; q < 2; ++q)
            __builtin_amdgcn_global_load_lds(
                (const __attribute__((address_space(1))) unsigned int*)(gq[q] + kbyte),
                (__attribute__((address_space(3))) unsigned int*)lq[q], 16, 0, 0);
        __syncthreads();
#pragma unroll
        for (int s = 0; s < 2; ++s) {
            int k0 = s * 32 + 4 * g;
            bf16x8 af = load_frag(sA, wy * 16 + cl, k0);
            bf16x8 bf = load_frag(sB, wx * 16 + cl, k0);
            acc = __builtin_amdgcn_mfma_f32_16x16x32_bf16(af, bf, acc, 0, 0, 0);
        }
    }

    float inv = s_inv;                     // written before first barrier; visible
    int col = c0 + wx * 16 + cl;
    float bb = bias[col];
    int row0 = n0 + wy * 16 + 4 * g;
#pragma unroll
    for (int r = 0; r < 4; ++r)
        M[(size_t)(row0 + r) * OKD + col] = acc[r] * inv + bb;
}

// ---- K6: ob[n,o] = sum_j exp(-L1(m[n,o,:], m[j,o,:])) - 1 ----
// grid (64 o, 8 n-chunks of 32) x 256 thr; 8 lanes cooperate per n over j
__global__ __launch_bounds__(256) void k_pair(const float* __restrict__ M,
                                              float* __restrict__ ob) {
    __shared__ float sm[NB * KD];   // 16 KB, XOR-swizzled by row
    int o = blockIdx.x, tid = threadIdx.x;
    const float4* M4 = (const float4*)M;
    float4* sm4 = (float4*)sm;
#pragma unroll
    for (int tq = 0; tq < 4; ++tq) {
        int idx = tid + tq * 256;          // 1024 float4
        int j = idx >> 2, k4 = idx & 3;
        sm4[j * 4 + (k4 ^ (j & 3))] = M4[(size_t)j * 256 + o * 4 + k4];
    }
    __syncthreads();
    int n = blockIdx.y * 32 + (tid >> 3);
    int jc = tid & 7;
    int nx = (n & 3) << 2;
    float r[KD];
#pragma unroll
    for (int k = 0; k < KD; ++k) r[k] = sm[n * 16 + (k ^ nx)];
    float acc = 0.f;
    for (int jj = 0; jj < 32; ++jj) {
        int j = jj * 8 + jc;
        int base = j * 16, jx = (j & 3) << 2;
        float d = 0.f;
#pragma unroll
        for (int k = 0; k < KD; ++k) d += fabsf(r[k] - sm[base + (k ^ jx)]);
        acc += __expf(-d);
    }
    acc += __shfl_xor(acc, 1);
    acc += __shfl_xor(acc, 2);
    acc += __shfl_xor(acc, 4);
    if (jc == 0) ob[n * OUTF + o] = acc - 1.0f;
}

// ---- K7: out[n,l,:] = concat(x[n,l,:], ob[n,:]) ----
__global__ void k_out(const float* __restrict__ X, const float* __restrict__ ob,
                      float4* __restrict__ out4) {
    int q = blockIdx.x * 256 + threadIdx.x;
    int r = q / 24;
    int c = q - r * 24;
    if (c < 8) {
        out4[q] = ((const float4*)X)[(size_t)r * 8 + c];
    } else {
        int n = r >> 6;
        out4[q] = ((const float4*)ob)[n * 16 + (c - 8)];
    }
}

extern "C" void kernel_launch(void* const* d_in, const int* in_sizes, int n_in,
                              void* d_out, int out_size, void* d_ws, size_t ws_size,
                              hipStream_t stream) {
    const float* x = (const float*)d_in[0];   // 256*64*32
    const float* W = (const float*)d_in[1];   // 1024*2048
    const float* b = (const float*)d_in[2];   // 1024
    const float* u = (const float*)d_in[3];   // 1024

    float* ws = (float*)d_ws;
    // time-shared regions (producer dies before next user writes):
    float* M        = ws;                  // 262144   (gemm -> pair)
    float* partial  = ws;                  // 128*2048 (vraw_cast -> vredx), dies before M
    float* ob       = ws + 262144;         // 16384    (pair -> out)
    float* partial2 = ws + 262144;         // 2*2048   (vredx -> vnorm), dies before ob
    float* v        = ws + 278528;         // 2048
    float* tpart    = ws + 280576;         // 512
    unsigned short* Wb = (unsigned short*)(ws + 281088);   // 2M bf16 (4MB)
    unsigned short* xb = (unsigned short*)(ws + 1329664);  // 512K bf16 (1MB)
    // total: 1591808 floats = 6.07 MB (under previously-proven ws capacity)

    k_vraw_cast<<<128, 256, 0, stream>>>(W, u, partial, Wb);
    k_vredx    <<<272, 256, 0, stream>>>(partial, partial2, x, xb);
    k_vnorm    <<<1,   256, 0, stream>>>(partial2, v);
    k_t        <<<512, 256, 0, stream>>>(Wb, v, tpart);
    k_gemm     <<<dim3(32, 8), 256, 0, stream>>>(xb, Wb, tpart, b, M);
    k_pair     <<<dim3(64, 8), 256, 0, stream>>>(M, ob);
    k_out      <<<1536, 256, 0, stream>>>(x, ob, (float4*)d_out);
}

// Round 9
// 102.258 us; speedup vs baseline: 1.7634x; 1.0253x over previous
//
#include <hip/hip_runtime.h>
#include <hip/hip_bf16.h>
#include <math.h>

#define KIN  2048
#define OKD  1024
#define NB   256
#define OUTF 64
#define KD   16

typedef float f32x4  __attribute__((ext_vector_type(4)));
typedef short bf16x4 __attribute__((ext_vector_type(4)));
typedef short bf16x8 __attribute__((ext_vector_type(8)));
typedef unsigned short u16x8 __attribute__((ext_vector_type(8)));

static __device__ __forceinline__ unsigned short f2bf(float f) {
    union { __hip_bfloat16 b; unsigned short u; } cv;
    cv.b = __float2bfloat16(f);
    return cv.u;
}
static __device__ __forceinline__ u16x8 pack8(float4 a, float4 b) {
    u16x8 r;
    r[0]=f2bf(a.x); r[1]=f2bf(a.y); r[2]=f2bf(a.z); r[3]=f2bf(a.w);
    r[4]=f2bf(b.x); r[5]=f2bf(b.y); r[6]=f2bf(b.z); r[7]=f2bf(b.w);
    return r;
}
static __device__ __forceinline__ float bf2f(unsigned short u) {
    union { unsigned int i; float f; } cv; cv.i = ((unsigned int)u) << 16; return cv.f;
}

// ==== K1 (grid 416): bid<256: W cast + 4-row partials of W^T u
//                     256..287: x -> bf16 cast
//                     288..415: x -> out copy (c<8 float4 of each 24-float4 row)
__global__ __launch_bounds__(256) void k_stage1(const float* __restrict__ W,
        const float* __restrict__ u, const float* __restrict__ x,
        float* __restrict__ partial, unsigned short* __restrict__ Wb,
        unsigned short* __restrict__ xb, float4* __restrict__ out4) {
    int bid = blockIdx.x, tid = threadIdx.x;
    if (bid < 256) {
        int row0 = bid * 4;
        int c = tid * 8;
        float s[8];
#pragma unroll
        for (int i = 0; i < 8; ++i) s[i] = 0.f;
#pragma unroll
        for (int r = 0; r < 4; ++r) {
            int row = row0 + r;
            const float4* src = (const float4*)(W + (size_t)row * KIN + c);
            float4 f0 = src[0], f1 = src[1];
            *(u16x8*)(Wb + (size_t)row * KIN + c) = pack8(f0, f1);
            float uu = u[row];
            s[0] += f0.x * uu; s[1] += f0.y * uu; s[2] += f0.z * uu; s[3] += f0.w * uu;
            s[4] += f1.x * uu; s[5] += f1.y * uu; s[6] += f1.z * uu; s[7] += f1.w * uu;
        }
        float4* dst = (float4*)(partial + (size_t)bid * KIN + c);
        dst[0] = make_float4(s[0], s[1], s[2], s[3]);
        dst[1] = make_float4(s[4], s[5], s[6], s[7]);
    } else if (bid < 288) {
        int xc = bid - 256;
        const float4* x4 = (const float4*)x;
#pragma unroll
        for (int p = 0; p < 8; ++p) {
            int g = xc * 2048 + p * 256 + tid;      // 32*2048 = 65536 packs of 8
            float4 f0 = x4[(size_t)g * 2], f1 = x4[(size_t)g * 2 + 1];
            *((u16x8*)xb + g) = pack8(f0, f1);
        }
    } else {
        int xo = bid - 288;
        const float4* x4 = (const float4*)x;
#pragma unroll
        for (int p = 0; p < 4; ++p) {
            int i = xo * 1024 + p * 256 + tid;      // 128*1024 = 131072 float4 of x
            int r = i >> 3, c = i & 7;
            out4[(size_t)r * 24 + c] = x4[i];
        }
    }
}

// ==== K2 (grid 16): reduce partial[256][2048] -> partial2[2][2048]
__global__ __launch_bounds__(256) void k_vred(const float* __restrict__ partial,
                                              float* __restrict__ partial2) {
    int bid = blockIdx.x, tid = threadIdx.x;
    int bg = bid & 1, cg = bid >> 1;
    int col = cg * 256 + tid;
    float a = 0.f;
#pragma unroll 8
    for (int i = 0; i < 128; ++i)
        a += partial[(size_t)(bg * 128 + i) * KIN + col];
    partial2[bg * KIN + col] = a;
}

// ==== K3 (grid 768): bid<256: MFMA GEMM P = xb * Wb^T (raw, no sigma/bias),
//                              32x32 tile, 2-phase double-buffered pipeline
//                     bid>=256: tpart[tb] = (r0.vraw)^2+(r1.vraw)^2; tpart[512]=|vraw|^2
// frag layout (16x16x32 bf16): A/B row|col = lane&15, k = 4*(lane>>4)+{0..3} and +16
// C/D: col = lane&15, row = 4*(lane>>4)+reg
static __device__ __forceinline__ bf16x8 load_frag(const unsigned short* lds, int row, int k0) {
    int b0 = (row << 7) + (k0 << 1);
    b0 ^= (row & 7) << 4;                 // XOR swizzle (bank-conflict fix)
    bf16x4 lo = *(const bf16x4*)((const char*)lds + b0);
    bf16x4 hi = *(const bf16x4*)((const char*)lds + (b0 ^ 32)); // +16 k (XOR commutes w/ swizzle)
    bf16x8 r;
    r[0]=lo[0]; r[1]=lo[1]; r[2]=lo[2]; r[3]=lo[3];
    r[4]=hi[0]; r[5]=hi[1]; r[6]=hi[2]; r[7]=hi[3];
    return r;
}

__global__ __launch_bounds__(256) void k_tg(const unsigned short* __restrict__ xb,
        const unsigned short* __restrict__ Wb, const float* __restrict__ partial2,
        float* __restrict__ tpart, float* __restrict__ P) {
    __shared__ unsigned short sAB[2][4096];   // 2 x (A 32x64 | B 32x64) bf16
    __shared__ float part[4], part2s[4];
    int bid = blockIdx.x, tid = threadIdx.x;
    int lane = tid & 63, w = tid >> 6;

    if (bid >= 256) {
        // ---- t-path: dot W row with vraw (= partial2[0]+partial2[1]) ----
        int tb = bid - 256;
        int row = tb * 2 + (w >> 1);
        int h = w & 1;
        const u16x8* W8 = (const u16x8*)(Wb + (size_t)row * KIN + h * 1024);
        const float4* pa = (const float4*)(partial2 + h * 1024);
        const float4* pb = (const float4*)(partial2 + KIN + h * 1024);
        float s = 0.f, s2 = 0.f;
#pragma unroll
        for (int q = 0; q < 2; ++q) {
            int idx = q * 64 + lane;
            u16x8 a = W8[idx];
            float4 a0 = pa[idx * 2], a1 = pa[idx * 2 + 1];
            float4 b0 = pb[idx * 2], b1 = pb[idx * 2 + 1];
            float v0 = a0.x + b0.x, v1 = a0.y + b0.y, v2 = a0.z + b0.z, v3 = a0.w + b0.w;
            float v4 = a1.x + b1.x, v5 = a1.y + b1.y, v6 = a1.z + b1.z, v7 = a1.w + b1.w;
            s += bf2f(a[0])*v0 + bf2f(a[1])*v1 + bf2f(a[2])*v2 + bf2f(a[3])*v3;
            s += bf2f(a[4])*v4 + bf2f(a[5])*v5 + bf2f(a[6])*v6 + bf2f(a[7])*v7;
            s2 += v0*v0 + v1*v1 + v2*v2 + v3*v3 + v4*v4 + v5*v5 + v6*v6 + v7*v7;
        }
#pragma unroll
        for (int off = 32; off; off >>= 1) { s += __shfl_xor(s, off); s2 += __shfl_xor(s2, off); }
        if (lane == 0) { part[w] = s; part2s[w] = s2; }
        __syncthreads();
        if (tid == 0) {
            float r0 = part[0] + part[1], r1 = part[2] + part[3];
            tpart[tb] = r0 * r0 + r1 * r1;
            if (tb == 0) tpart[512] = part2s[0] + part2s[1];  // |vraw|^2
        }
        return;
    }

    // ---- gemm path ----
    int c0 = (bid & 31) * 32, n0 = (bid >> 5) * 32;

    const char* gq[2];
    int lqo[2];
#pragma unroll
    for (int q = 0; q < 2; ++q) {
        int ch = q * 4 + w;
        int p = ch * 1024 + lane * 16;     // byte pos in 8KB tile region
        int rp = p & 4095;
        int row = rp >> 7;                 // 128B per row (64 bf16)
        int off = (rp & 127) ^ ((row & 7) << 4);   // inverse-swizzled source
        const unsigned short* base = (p < 4096) ? xb : Wb;
        int grow = (p < 4096) ? (n0 + row) : (c0 + row);
        gq[q] = (const char*)(base + (size_t)grow * KIN) + off;
        lqo[q] = ch * 512;                 // u16 offset within one buffer
    }

    int g = lane >> 4, cl = lane & 15;
    int wy = w >> 1, wx = w & 1;
    f32x4 acc;
#pragma unroll
    for (int r = 0; r < 4; ++r) acc[r] = 0.f;

    // prologue: stage tile 0 into buf0
#pragma unroll
    for (int q = 0; q < 2; ++q)
        __builtin_amdgcn_global_load_lds(
            (const __attribute__((address_space(1))) unsigned int*)(gq[q]),
            (__attribute__((address_space(3))) unsigned int*)(&sAB[0][lqo[q]]), 16, 0, 0);
    __syncthreads();

    for (int t = 0; t < 32; ++t) {
        int cur = t & 1;
        if (t < 31) {
            int kb = (t + 1) * 128;
#pragma unroll
            for (int q = 0; q < 2; ++q)
                __builtin_amdgcn_global_load_lds(
                    (const __attribute__((address_space(1))) unsigned int*)(gq[q] + kb),
                    (__attribute__((address_space(3))) unsigned int*)(&sAB[cur ^ 1][lqo[q]]), 16, 0, 0);
        }
        const unsigned short* sA = sAB[cur];
        const unsigned short* sB = sAB[cur] + 2048;
#pragma unroll
        for (int s = 0; s < 2; ++s) {
            int k0 = s * 32 + 4 * g;
            bf16x8 af = load_frag(sA, wy * 16 + cl, k0);
            bf16x8 bf = load_frag(sB, wx * 16 + cl, k0);
            acc = __builtin_amdgcn_mfma_f32_16x16x32_bf16(af, bf, acc, 0, 0, 0);
        }
        __syncthreads();   // drains vmcnt (next-tile stage) + lgkm; WAR-safe
    }

    int col = c0 + wx * 16 + cl;
    int row0 = n0 + wy * 16 + 4 * g;
#pragma unroll
    for (int r = 0; r < 4; ++r)
        P[(size_t)(row0 + r) * OKD + col] = acc[r];
}

// ==== K4 (grid 64 x 8): ob[n,o] = sum_j exp(-invs * sum_k |P[n,o,k]-P[j,o,k]|) - 1
__global__ __launch_bounds__(256) void k_pair(const float* __restrict__ M,
        const float* __restrict__ tpart, float* __restrict__ ob) {
    __shared__ float sm[NB * KD];   // 16 KB, XOR-swizzled by row
    __shared__ float sred[4];
    int o = blockIdx.x, tid = threadIdx.x;

    // sigma partial reduce (pre-barrier)
    float tv = tpart[tid] + tpart[tid + 256];
#pragma unroll
    for (int off = 32; off; off >>= 1) tv += __shfl_xor(tv, off);
    if ((tid & 63) == 0) sred[tid >> 6] = tv;

    const float4* M4 = (const float4*)M;
    float4* sm4 = (float4*)sm;
#pragma unroll
    for (int tq = 0; tq < 4; ++tq) {
        int idx = tid + tq * 256;          // 1024 float4
        int j = idx >> 2, k4 = idx & 3;
        sm4[j * 4 + (k4 ^ (j & 3))] = M4[(size_t)j * 256 + o * 4 + k4];
    }
    __syncthreads();

    float ssum = sred[0] + sred[1] + sred[2] + sred[3];
    float nv2 = tpart[512];
    float ssq = ssum / nv2;                       // = |W v|^2
    float invs = (sqrtf(ssq) + 1e-12f) / ssq;     // = 1/sigma

    int n = blockIdx.y * 32 + (tid >> 3);
    int jc = tid & 7;
    int nx = (n & 3) << 2;
    float r[KD];
#pragma unroll
    for (int k = 0; k < KD; ++k) r[k] = sm[n * 16 + (k ^ nx)];
    float acc = 0.f;
    for (int jj = 0; jj < 32; ++jj) {
        int j = jj * 8 + jc;
        int base = j * 16, jx = (j & 3) << 2;
        float d = 0.f;
#pragma unroll
        for (int k = 0; k < KD; ++k) d += fabsf(r[k] - sm[base + (k ^ jx)]);
        acc += __expf(-d * invs);
    }
    acc += __shfl_xor(acc, 1);
    acc += __shfl_xor(acc, 2);
    acc += __shfl_xor(acc, 4);
    if (jc == 0) ob[n * OUTF + o] = acc - 1.0f;
}

// ==== K5 (grid 256): out[n,l, 32..96) = ob[n,:]  (16 float4 of each 24-float4 row)
__global__ void k_obout(const float* __restrict__ ob, float4* __restrict__ out4) {
    int bid = blockIdx.x, tid = threadIdx.x;
    const float4* ob4 = (const float4*)ob;
#pragma unroll
    for (int p = 0; p < 4; ++p) {
        int i = bid * 1024 + p * 256 + tid;     // 256*1024 = 262144 = 16384 rows x 16
        int r = i >> 4, c2 = i & 15;
        out4[(size_t)r * 24 + 8 + c2] = ob4[(r >> 6) * 16 + c2];
    }
}

extern "C" void kernel_launch(void* const* d_in, const int* in_sizes, int n_in,
                              void* d_out, int out_size, void* d_ws, size_t ws_size,
                              hipStream_t stream) {
    const float* x = (const float*)d_in[0];   // 256*64*32
    const float* W = (const float*)d_in[1];   // 1024*2048
    // d_in[2] = bias: cancels exactly in m[i]-m[j] -> unused
    const float* u = (const float*)d_in[3];   // 1024

    float* ws = (float*)d_ws;
    float* partial  = ws;                   // 256*2048 = 524288  (K1 -> K2, dies)
    float* P        = ws;                   // 262144 (K3 -> K4), aliases dead partial
    float* partial2 = ws + 524288;          // 4096
    float* tpart    = ws + 528384;          // 513 (tpart[512] = |vraw|^2)
    float* ob       = ws + 529408;          // 16384
    unsigned short* Wb = (unsigned short*)(ws + 545792);   // 2M bf16 (4MB)
    unsigned short* xb = (unsigned short*)(ws + 1594368);  // 512K bf16 (1MB)
    // total 1856512 floats = 7.08 MB

    k_stage1<<<416, 256, 0, stream>>>(W, u, x, partial, Wb, xb, (float4*)d_out);
    k_vred  <<<16,  256, 0, stream>>>(partial, partial2);
    k_tg    <<<768, 256, 0, stream>>>(xb, Wb, partial2, tpart, P);
    k_pair  <<<dim3(64, 8), 256, 0, stream>>>(P, tpart, ob);
    k_obout <<<256, 256, 0, stream>>>(ob, (float4*)d_out);
}